// Round 1
// baseline (202.388 us; speedup 1.0000x reference)
//
#include <hip/hip_runtime.h>
#include <math.h>

#define N_BOXES 256
#define N_VIEWS 6
#define C_FEAT 256
#define HF 116
#define WF 200
#define FEAT_HW (HF * WF)
#define P_TOT (N_BOXES * N_VIEWS)
#define EPS_F 1e-8f

// Workspace (re-poisoned to 0xAA before every timed call; every field written each call)
struct WsLayout {
    int   count;           // n_pairs
    int   pad[15];
    float loss[P_TOT];     // per-point masked loss (0 if inactive)
};

__device__ __forceinline__ float wave_reduce_sum(float v) {
    #pragma unroll
    for (int off = 32; off > 0; off >>= 1)
        v += __shfl_down(v, off, 64);
    return v;
}

// Project point p (= box n, view v), return packed code:
// bit31 = valid, bits[15:9] = v0c (row), bits[8:0] = u0c (col).
// Pure ALU from ~8 KB of L1/L2-resident inputs — cheap to recompute per block.
__device__ __forceinline__ int project_pack(
    const float* __restrict__ boxes, const float* __restrict__ Km,
    const float* __restrict__ Tm, const int* __restrict__ img, int p)
{
    const int n = p / N_VIEWS, v = p - n * N_VIEWS;
    const float cx = boxes[n * 7 + 0];
    const float cy = boxes[n * 7 + 1];
    const float cz = boxes[n * 7 + 2];
    const float* Tv = Tm + v * 16;
    const float* Kv = Km + v * 9;
    float pc[3];
    #pragma unroll
    for (int i = 0; i < 3; ++i)
        pc[i] = Tv[i * 4 + 0] * cx + Tv[i * 4 + 1] * cy + Tv[i * 4 + 2] * cz + Tv[i * 4 + 3];
    float p2[3];
    #pragma unroll
    for (int i = 0; i < 3; ++i)
        p2[i] = Kv[i * 3 + 0] * pc[0] + Kv[i * 3 + 1] * pc[1] + Kv[i * 3 + 2] * pc[2];
    const float z  = pc[2];
    const float uu = p2[0] / p2[2];
    const float vv = p2[1] / z;
    const float Wimg = (float)img[v * 2 + 1];
    const float Himg = (float)img[v * 2 + 0];
    const int u0 = (int)floorf(uu * (float)WF / Wimg);
    const int v0 = (int)floorf(vv * (float)HF / Himg);
    const bool valid = (z > 0.f) && (uu >= 0.f) && (uu < Wimg) &&
                       (vv >= 0.f) && (vv < Himg) &&
                       (u0 < WF - 1) && (v0 < HF - 1);
    const int u0c = min(max(u0, 0), WF - 2);
    const int v0c = min(max(v0, 0), HF - 2);
    return u0c | (v0c << 9) | (valid ? (int)0x80000000 : 0);
}

// Main kernel: 384 blocks x 256 threads (4 waves), one WAVE per point.
// Order of operations is chosen so the scattered own-point loads are issued
// FIRST and their latency hides under phase-1 ALU + the LDS first-gather:
//   1. project own point, issue its 16 scattered loads into registers
//   2. phase 1: block-redundant first/count over all 1536 points (pure ALU)
//   3. gather the `first` point's 256-channel fm ONCE per block into LDS
//      (256 threads x 4 loads — replaces 16 L2-hot loads per LANE before),
//      plus one block-wide snsq reduction
//   4. per-wave: dot/nsq from preloaded regs + LDS fmf, write loss[p]
__global__ __launch_bounds__(256) void fused_kernel(
    const float* __restrict__ boxes,   // (N,7)
    const float* __restrict__ feats,   // (V,C,HF,WF)
    const float* __restrict__ Km,      // (V,3,3)
    const float* __restrict__ Tm,      // (V,4,4)
    const int*   __restrict__ img,     // (V,2) [H,W]
    WsLayout*    __restrict__ ws)
{
    const int tid  = threadIdx.x;
    const int lane = tid & 63;
    const int wave = tid >> 6;

    __shared__ int   s_min[4], s_cnt[4];
    __shared__ float s_fmf[C_FEAT];
    __shared__ float s_red[4];

    // ---- 1. Own-point projection + early scattered prefetch ----
    const int p = blockIdx.x * 4 + wave;
    const int pk_p = project_pack(boxes, Km, Tm, img, p);
    const bool pvalid = (pk_p < 0);
    float r0[4], r1[4], r2[4], r3[4];
    if (pvalid) {
        const int xp = pk_p & 0x1ff, yp = (pk_p >> 9) & 0x7f;
        const int vp = p % N_VIEWS;
        const float* basep = feats + ((size_t)(vp * C_FEAT) * HF + yp) * WF + xp;
        #pragma unroll
        for (int j = 0; j < 4; ++j) {
            const float* bp = basep + (size_t)(lane + 64 * j) * FEAT_HW;
            r0[j] = bp[0];
            r1[j] = bp[1];
            r2[j] = bp[WF];
            r3[j] = bp[WF + 1];
        }
    }

    // ---- 2. Phase 1: first = argmax(valid), count = n_valid (block-redundant ALU) ----
    int localmin = 0x7fffffff;
    int localcnt = 0;
    #pragma unroll
    for (int i = 0; i < P_TOT / 256; ++i) {
        const int q  = tid + 256 * i;
        const int pk = project_pack(boxes, Km, Tm, img, q);
        if (pk < 0) { ++localcnt; if (q < localmin) localmin = q; }
    }
    #pragma unroll
    for (int off = 32; off > 0; off >>= 1) {
        localmin = min(localmin, __shfl_down(localmin, off, 64));
        localcnt += __shfl_down(localcnt, off, 64);
    }
    if (lane == 0) { s_min[wave] = localmin; s_cnt[wave] = localcnt; }
    __syncthreads();
    const int gmin = min(min(s_min[0], s_min[1]), min(s_min[2], s_min[3]));
    const int gcnt = s_cnt[0] + s_cnt[1] + s_cnt[2] + s_cnt[3];
    const bool any_valid = (gmin != 0x7fffffff);
    const int first = any_valid ? gmin : 0;

    if (blockIdx.x == 0 && tid == 0)
        ws->count = gcnt - (any_valid ? 1 : 0);

    // ---- 3. Stored-point gather ONCE per block, channel = tid ----
    const int pk_f = project_pack(boxes, Km, Tm, img, first);
    const int xf = pk_f & 0x1ff, yf = (pk_f >> 9) & 0x7f;
    const int vf = first % N_VIEWS;
    const float* bf = feats + (((size_t)(vf * C_FEAT) + tid) * HF + yf) * WF + xf;
    const float fmf = 0.25f * (bf[0] + bf[1] + bf[WF] + bf[WF + 1]);
    s_fmf[tid] = fmf;
    const float sn = wave_reduce_sum(fmf * fmf);
    if (lane == 0) s_red[wave] = sn;
    __syncthreads();
    const float snsq = s_red[0] + s_red[1] + s_red[2] + s_red[3];

    // ---- 4. Per-wave cosine vs stored ----
    const bool active = pvalid && (p != first);
    float dot = 0.f, nsq = 0.f;
    if (active) {
        #pragma unroll
        for (int j = 0; j < 4; ++j) {
            const float fmp = 0.25f * (r0[j] + r1[j] + r2[j] + r3[j]);
            dot += fmp * s_fmf[lane + 64 * j];
            nsq += fmp * fmp;
        }
    }
    dot = wave_reduce_sum(dot);
    nsq = wave_reduce_sum(nsq);

    if (lane == 0) {
        float l = 0.f;
        if (active)
            l = 1.0f - dot / (fmaxf(sqrtf(nsq), EPS_F) * fmaxf(sqrtf(snsq), EPS_F));
        ws->loss[p] = l;
    }
}

// Finish: single block reduces the 1536 per-point losses, divides, writes out.
__global__ __launch_bounds__(256) void finish_kernel(
    const WsLayout* __restrict__ ws,
    float*          __restrict__ out)
{
    __shared__ float s_red[4];
    const int tid = threadIdx.x;
    float s = 0.f;
    #pragma unroll
    for (int i = 0; i < P_TOT / 256; ++i) s += ws->loss[tid + 256 * i];
    s = wave_reduce_sum(s);
    const int lane = tid & 63, wave = tid >> 6;
    if (lane == 0) s_red[wave] = s;
    __syncthreads();
    if (tid == 0) {
        const float total = s_red[0] + s_red[1] + s_red[2] + s_red[3];
        const int   cnt   = ws->count;
        out[0] = (cnt > 0) ? total / (float)cnt : 0.0f;
    }
}

extern "C" void kernel_launch(void* const* d_in, const int* in_sizes, int n_in,
                              void* d_out, int out_size, void* d_ws, size_t ws_size,
                              hipStream_t stream) {
    const float* boxes = (const float*)d_in[0];
    const float* feats = (const float*)d_in[1];
    const float* Km    = (const float*)d_in[2];
    const float* Tm    = (const float*)d_in[3];
    const int*   img   = (const int*)d_in[4];
    float* out = (float*)d_out;
    WsLayout* ws = (WsLayout*)d_ws;

    hipLaunchKernelGGL(fused_kernel, dim3(P_TOT / 4), dim3(256), 0, stream,
                       boxes, feats, Km, Tm, img, ws);
    hipLaunchKernelGGL(finish_kernel, dim3(1), dim3(256), 0, stream,
                       ws, out);
}